// Round 2
// baseline (230.473 us; speedup 1.0000x reference)
//
#include <hip/hip_runtime.h>

// CBFHalfspace: h(x)=b-Ax with A[:,0:2]=[[-1,0],[1,0],[0,-1],[0,1]], b=[1,1,1,1].
// h is affine and A's column sums are zero => grad(sum h)==0 identically, so
// Lfh = Lf2h = LgLfh = 0 exactly. Per-row output (8 floats):
//   [1+x0, 1-x0, 1+x1, 1-x1, 0, 0, 0, 0]
//
// Traffic floor: ~117 MB read of x (prev rocprof: FETCH=65 MB, ~52 MB L3-hit
// from the harness restore copy) + 134 MB NT-write of out ≈ 200 MB HBM ≈ 32 us.
//
// Round-3 structure: 512 rows per 256-thread block (2 rows in flight per
// thread before the single barrier) -> 32768 waves instead of 65536, fewer
// barriers, more memory-level parallelism per wave. Store pattern unchanged:
// unit-stride float4 NT stores so every wave instruction covers full 64B
// lines (required for nontemporal write-combining; avoids RMW at HBM and
// avoids allocating into the poison-dirty L3).
//
// NOTE: x rows are 28B apart -> rows at odd index are only 4B-aligned, so we
// keep two scalar dword loads per row (a dwordx2 would be misaligned UB).
// Loads stay regular (not NT) to keep the ~52 MB of L3 hits on x.

typedef float v4f __attribute__((ext_vector_type(4)));

__global__ __launch_bounds__(256) void CBFHalfspace_68917045231689_kernel(
        const float* __restrict__ x, v4f* __restrict__ out4) {
    __shared__ v4f hbuf[512];

    const int t = threadIdx.x;
    const int rbase = blockIdx.x * 512;   // B = 4,194,304, divisible by 512

    // Two rows per thread: rbase+t and rbase+256+t. Issue all four loads
    // before any use so both rows' loads are in flight together.
    const int r0 = rbase + t;
    const int r1 = rbase + 256 + t;      // r1*7+1 <= 29,360,129 -> int32 ok
    const float a0 = x[r0 * 7 + 0];
    const float a1 = x[r0 * 7 + 1];
    const float c0 = x[r1 * 7 + 0];
    const float c1 = x[r1 * 7 + 1];
    hbuf[t]       = (v4f){1.0f + a0, 1.0f - a0, 1.0f + a1, 1.0f - a1};
    hbuf[t + 256] = (v4f){1.0f + c0, 1.0f - c0, 1.0f + c1, 1.0f - c1};
    __syncthreads();

    const v4f z = (v4f){0.0f, 0.0f, 0.0f, 0.0f};
    // Block owns 1024 consecutive float4 slots: slot s even -> h(row s/2),
    // odd -> zeros. Each wave store instruction is unit-stride (1 KiB, full
    // 64B lines).
    const size_t base = (size_t)blockIdx.x * 1024;
#pragma unroll
    for (int i = 0; i < 4; ++i) {
        const int s = t + 256 * i;       // parity(s) == parity(t)
        v4f v = (s & 1) ? z : hbuf[s >> 1];
        __builtin_nontemporal_store(v, &out4[base + s]);
    }
}

extern "C" void kernel_launch(void* const* d_in, const int* in_sizes, int n_in,
                              void* d_out, int out_size, void* d_ws, size_t ws_size,
                              hipStream_t stream) {
    const float* x = (const float*)d_in[0];
    // d_in[1] (f) and d_in[2] (g) are mathematically irrelevant: grad(sum h)=0.
    v4f* out4 = (v4f*)d_out;

    const int B = in_sizes[0] / 7;           // 4,194,304 rows
    const int grid = B / 512;                // 8192 blocks; B % 512 == 0
    CBFHalfspace_68917045231689_kernel<<<grid, 256, 0, stream>>>(x, out4);
}

// Round 3
// 219.262 us; speedup vs baseline: 1.0511x; 1.0511x over previous
//
#include <hip/hip_runtime.h>

// CBFHalfspace: h(x)=b-Ax, A[:,0:2]=[[-1,0],[1,0],[0,-1],[0,1]], b=1.
// h affine, A column-sums zero => all Lie-derivative outputs are exactly 0.
// Per-row output (8 floats): [1+x0, 1-x0, 1+x1, 1-x1, 0, 0, 0, 0].
//
// Round-3 evidence: kernel dispatch 78.9 us, FETCH=154 MB (> x's 117 MB: the
// 537 MB poison fill runs between x-restore and us, so NO L3 hits on x), and
// effective BW only 3.7 TB/s vs the 6.7 TB/s the fill kernel gets.
// Diagnosis: (a) regular loads allocate x into the poison-dirty L3, forcing
// ~1 dirty-poison eviction write per allocated line (~100+ MB hidden traffic);
// (b) scalar dword loads at 28 B stride touch each 64 B line ~2.3x across two
// load instructions (L2 absorbs it, but issue efficiency is poor).
//
// Round-4 structure:
//   - NT (non-allocating) dwordx4 LOADS of x, unit-stride, staged to LDS:
//     117 MB streamed exactly once, no L3 pollution, no poison evictions.
//   - h computed at store time straight from LDS (stride-7 float reads:
//     7 coprime to 32 banks => conflict-free). No h staging buffer.
//   - NT dwordx4 STORES, unit-stride, full 64 B lines (as before).
// 1024 rows / 256-thread block: 7 load-f4 + 8 store-f4 per thread, 28 KB LDS
// (5 blocks/CU), 4096 blocks.

typedef float v4f __attribute__((ext_vector_type(4)));

#define THREADS 256
#define RPB     1024                       // rows per block; B % 1024 == 0
#define XF4     (RPB * 7 / 4)              // 1792 float4 of x per block
#define OF4     (RPB * 2)                  // 2048 float4 of out per block

__global__ __launch_bounds__(256) void CBFHalfspace_68917045231689_kernel(
        const v4f* __restrict__ x4, v4f* __restrict__ out4) {
    __shared__ float xs[RPB * 7];          // 28672 B
    v4f* xs4 = (v4f*)xs;

    const int t = threadIdx.x;
    const size_t xbase = (size_t)blockIdx.x * XF4;

    // Stage this block's 28672 B slice of x: unit-stride NT float4 loads.
#pragma unroll
    for (int i = 0; i < 7; ++i) {
        const int idx = t + THREADS * i;
        xs4[idx] = __builtin_nontemporal_load(&x4[xbase + idx]);
    }
    __syncthreads();

    const v4f z = (v4f){0.0f, 0.0f, 0.0f, 0.0f};
    const size_t obase = (size_t)blockIdx.x * OF4;
    // Slot s (float4): even -> h(row s/2), odd -> zeros. parity(s)==parity(t),
    // so the branch is uniform per lane across all iterations.
#pragma unroll
    for (int i = 0; i < 8; ++i) {
        const int s = t + THREADS * i;
        v4f v = z;
        if (!(s & 1)) {
            const int r = s >> 1;          // row within block, 0..1023
            const float x0 = xs[r * 7 + 0];
            const float x1 = xs[r * 7 + 1];
            v = (v4f){1.0f + x0, 1.0f - x0, 1.0f + x1, 1.0f - x1};
        }
        __builtin_nontemporal_store(v, &out4[obase + s]);
    }
}

extern "C" void kernel_launch(void* const* d_in, const int* in_sizes, int n_in,
                              void* d_out, int out_size, void* d_ws, size_t ws_size,
                              hipStream_t stream) {
    const v4f* x4 = (const v4f*)d_in[0];   // x is 256B-aligned; 117,440,512 B % 16 == 0
    // d_in[1] (f) and d_in[2] (g) are mathematically irrelevant: grad(sum h)=0.
    v4f* out4 = (v4f*)d_out;

    const int B = in_sizes[0] / 7 / 4;     // bytes -> rows: in_sizes is bytes? (see below)
    // in_sizes[0] is the element count of x (B*7 floats) in this harness:
    const int rows = in_sizes[0] / 7;      // 4,194,304
    (void)B;
    const int grid = rows / RPB;           // 4096 blocks
    CBFHalfspace_68917045231689_kernel<<<grid, THREADS, 0, stream>>>(x4, out4);
}